// Round 4
// baseline (310.595 us; speedup 1.0000x reference)
//
#include <hip/hip_runtime.h>
#include <math.h>

#define IMG_H 512
#define IMG_W 512
#define NCELL 64     // cells per dim (512/8)
#define NORI 9

// ---------------------------------------------------------------------------
// Bit-exact transcription of glibc/FDLIBM float atan / atan2 (flt-32 Sun code)
// — what numpy's np.arctan2 float32 loop resolves to on glibc <= 2.40.
// INLINED (verified passing rounds 2-3): runtime-indexed tables converted to
// selects so nothing spills to scratch. Reached only for ~5e-4 of pixels.
// ---------------------------------------------------------------------------
__device__ __forceinline__ float fdlibm_atanf_inl(float x) {
#pragma clang fp contract(off)
    const float one = 1.0f;
    int hx = __float_as_int(x);
    int ix = hx & 0x7fffffff;
    int id;
    if (ix >= 0x4c800000) {                 // |x| >= 2^26
        const float v = 1.5707962513e+00f + 7.5497894159e-08f;  // folded in f32
        return (hx > 0) ? v : -v;
    }
    if (ix < 0x3ee00000) {                  // |x| < 0.4375
        if (ix < 0x39800000) return x;      // |x| < 2^-12
        id = -1;
    } else {
        x = fabsf(x);
        if (ix < 0x3f980000) {              // |x| < 1.1875
            if (ix < 0x3f300000) { id = 0; x = (2.0f * x - one) / (2.0f + x); }
            else                 { id = 1; x = (x - one) / (x + one); }
        } else {
            if (ix < 0x401c0000) { id = 2; x = (x - 1.5f) / (one + 1.5f * x); }
            else                 { id = 3; x = -1.0f / x; }
        }
    }
    float z = x * x;
    float w = z * z;
    float s1 = z * (3.3333334327e-01f + w * (1.4285714924e-01f + w * (9.0908870101e-02f
             + w * (6.6610731184e-02f + w * (4.9768779427e-02f + w * 1.6285819933e-02f)))));
    float s2 = w * (-2.0000000298e-01f + w * (-1.1111110449e-01f + w * (-7.6918758452e-02f
             + w * (-5.8335702866e-02f + w * -3.6531571299e-02f))));
    if (id < 0) return x - x * (s1 + s2);
    const float hi = (id == 0) ? 4.6364760399e-01f : (id == 1) ? 7.8539812565e-01f
                   : (id == 2) ? 9.8279368877e-01f : 1.5707962513e+00f;
    const float lo = (id == 0) ? 5.0121582440e-09f : (id == 1) ? 3.7748947079e-08f
                   : (id == 2) ? 3.4473217170e-08f : 7.5497894159e-08f;
    z = hi - ((x * (s1 + s2) - lo) - x);
    return (hx < 0) ? -z : z;
}

__device__ __forceinline__ int fdlibm_bin_inl(float y, float x) {
#pragma clang fp contract(off)
    // exact reference chain: fdlibm atan2f -> f32 rad2deg -> numpy mod -> bin
    const float tiny   = 1.0e-30f;
    const float pi_o_2 = 1.5707963705e+00f;   // 0x3FC90FDB
    const float pi     = 3.1415927410e+00f;   // 0x40490FDB
    const float pi_lo  = -8.7422776573e-08f;  // 0xB3BBBD2E

    int hx = __float_as_int(x), ix = hx & 0x7fffffff;
    int hy = __float_as_int(y), iy = hy & 0x7fffffff;
    float th;
    if (hx == 0x3f800000) { th = fdlibm_atanf_inl(y); }    // x == 1.0
    else {
        int m = ((hy >> 31) & 1) | ((hx >> 30) & 2);       // 2*sign(x)+sign(y)
        if (iy == 0) {                                      // y == +-0
            switch (m) {
                case 0:
                case 1: th = y; break;
                case 2: th =  pi + tiny; break;
                default: th = -pi - tiny; break;
            }
        } else if (ix == 0) {
            th = (hy < 0) ? -pi_o_2 - tiny : pi_o_2 + tiny; // x == +-0
        } else {
            int k = (iy - ix) >> 23;
            float z;
            int mm = m;
            if (k > 26) {                                   // |y/x| > 2^26
                z = pi_o_2 + 0.5f * pi_lo;
                mm &= 1;
            } else if (k < -26 && hx < 0) {
                z = 0.0f;
            } else {
                z = fdlibm_atanf_inl(fabsf(y / x));
            }
            switch (mm) {
                case 0:  th = z; break;
                case 1:  th = -z; break;
                case 2:  th = pi - (z - pi_lo); break;
                default: th = (z - pi_lo) - pi; break;
            }
        }
    }
    const float RAD2DEG = (float)(180.0 / 3.14159265358979311600e+00);
    float m = fmodf(th * RAD2DEG, 180.0f);                  // numpy remainder semantics
    if (m < 0.0f) m += 180.0f;                              // (can round up to exactly 180)
    int o = (int)(m * 0.05f);
    if (o < 9) {                                            // exact boundary fix-up
        if (m < 20.0f * (float)o) --o;
        else if (m >= 20.0f * (float)(o + 1)) ++o;
    }
    return o;                                               // may be 9 (== exactly 180): no bin
}

// 6 float4 (24 floats = 8 RGB px) -> 8 gray values. Same FMA chain as the
// verified rounds: fma(b,GW2, fma(g,GW1, r*GW0)).
__device__ __forceinline__ void cvt8(const float4 R[6], float g[8]) {
#pragma clang fp contract(off)
    const float GW0 = 0.2125f, GW1 = 0.7154f, GW2 = 0.0721f;
    g[0] = __builtin_fmaf(R[0].z, GW2, __builtin_fmaf(R[0].y, GW1, R[0].x * GW0));
    g[1] = __builtin_fmaf(R[1].y, GW2, __builtin_fmaf(R[1].x, GW1, R[0].w * GW0));
    g[2] = __builtin_fmaf(R[2].x, GW2, __builtin_fmaf(R[1].w, GW1, R[1].z * GW0));
    g[3] = __builtin_fmaf(R[2].w, GW2, __builtin_fmaf(R[2].z, GW1, R[2].y * GW0));
    g[4] = __builtin_fmaf(R[3].z, GW2, __builtin_fmaf(R[3].y, GW1, R[3].x * GW0));
    g[5] = __builtin_fmaf(R[4].y, GW2, __builtin_fmaf(R[4].x, GW1, R[3].w * GW0));
    g[6] = __builtin_fmaf(R[5].x, GW2, __builtin_fmaf(R[4].w, GW1, R[4].z * GW0));
    g[7] = __builtin_fmaf(R[5].w, GW2, __builtin_fmaf(R[5].z, GW1, R[5].y * GW0));
}

// ---------------------------------------------------------------------------
// Kernel 1 v4: STREAMING histograms — no LDS, no barriers, no reductions.
// One wave per cell-row; lane t == cell t (owns px [8t,8t+8)). 3-row rolling
// register window, software-pipelined one row ahead (6 float4 = 96B/lane in
// flight per wave at all times). Column neighbors via 2 intra-wave shuffles.
// Grid 64x16 blocks x 256 thr (4 independent waves/block) = 16 waves/CU.
// Binning: verified sector cross-products + inlined exact fdlibm suspects.
// ---------------------------------------------------------------------------
__global__ __launch_bounds__(256, 4) void hog_hist_kernel(const float* __restrict__ x,
                                                          float* __restrict__ hist) {
#pragma clang fp contract(off)
    const int bid  = blockIdx.x;
    const int b    = bid >> 4;              // batch
    const int s    = bid & 15;              // stripe of 4 cell-rows
    const int q    = threadIdx.x >> 6;      // wave in block
    const int lane = threadIdx.x & 63;
    const int cr   = s * 4 + q;             // this wave's cell-row
    const int h0   = cr * 8;

    const float4* X4 = (const float4*)x + (size_t)b * (IMG_H * (IMG_W * 3 / 4));

    // row base for this lane, image rows mirror-clamped (=> gr == +0.0 at edges)
    auto rowp = [&](int h) -> const float4* {
        if (h < 0)   h = 1;
        if (h > 511) h = 510;
        return X4 + (size_t)h * (IMG_W * 3 / 4) + lane * 6;
    };

    // ---- prologue: rows h0-1, h0 (loads co-issued), then issue h0+1 ----
    float gp[8], gm[8], gn[8];
    {
        float4 R0[6], R1[6];
        const float4* p0 = rowp(h0 - 1);
        const float4* p1 = rowp(h0);
#pragma unroll
        for (int i = 0; i < 6; ++i) R0[i] = p0[i];
#pragma unroll
        for (int i = 0; i < 6; ++i) R1[i] = p1[i];
        cvt8(R0, gp);
        cvt8(R1, gm);
    }
    float4 P[6];
    {
        const float4* p = rowp(h0 + 1);
#pragma unroll
        for (int i = 0; i < 6; ++i) P[i] = p[i];
    }

    // sector boundary constants (20k degrees), f32-rounded
    const float CK[8] = { 0.9396926208f,  0.7660444431f,  0.5f,            0.1736481777f,
                         -0.1736481777f, -0.5f,           -0.7660444431f, -0.9396926208f };
    const float SK[8] = { 0.3420201433f,  0.6427876097f,  0.8660254038f,  0.9848077530f,
                          0.9848077530f,  0.8660254038f,  0.6427876097f,  0.3420201433f };

    float bh[9];
#pragma unroll
    for (int k = 0; k < 9; ++k) bh[k] = 0.0f;

#pragma unroll
    for (int j8 = 0; j8 < 8; ++j8) {
        const int h = h0 + j8;

        // (1) issue next-next row loads (in flight during this row's compute)
        float4 N[6];
        const bool pf = (j8 < 7);
        if (pf) {
            const float4* p = rowp(h + 2);
#pragma unroll
            for (int i = 0; i < 6; ++i) N[i] = p[i];
        }

        // (2) convert row h+1 (loaded last iteration)
        cvt8(P, gn);

        // (3) column-neighbor grays across lanes (row h)
        const float glft = __shfl_up(gm[7], 1, 64);    // lane t-1's px7
        const float grgt = __shfl_down(gm[0], 1, 64);  // lane t+1's px0

        // (4) 8 pixels of row h
#pragma unroll
        for (int j = 0; j < 8; ++j) {
            const int  w   = lane * 8 + j;
            const bool wok = (w >= 1) && (w <= 510);
            const float left  = (j == 0) ? glft : gm[j - 1];
            const float right = (j == 7) ? grgt : gm[j + 1];
            const float gr = gn[j] - gp[j];             // +0.0 at image edge rows
            const float gc = wok ? (right - left) : 0.0f;
            const float mag = __builtin_amdgcn_sqrtf(__builtin_fmaf(gr, gr, gc * gc));

            const float gy = fabsf(gr);
            const float gx = (gr < 0.0f) ? -gc : gc;    // theta mod 180 representative
            const float th = 1e-4f * mag;               // suspect margin (~0.006 deg)
            int  o = 0;
            bool suspect = false;
#pragma unroll
            for (int k = 0; k < 8; ++k) {
                const float ck = __builtin_fmaf(gy, CK[k], -(gx * SK[k]));
                o += (ck >= 0.0f) ? 1 : 0;
                suspect = suspect || (fabsf(ck) < th);
            }
            // f32 near-180 zone: atan2f can round to pi exactly -> ref deg>=180
            // -> mod wraps to bin 0 / no-bin. Sector test can't see this; defer.
            suspect = suspect || ((gx < 0.0f) && (gy < 1e-5f * fabsf(gc)));
            if (gy == 0.0f) { o = 0; suspect = false; } // exact: ref chain -> bin 0
            if (__builtin_expect(suspect, 0)) {
                o = fdlibm_bin_inl(gr, gc);             // inlined exact; may be 9
            }
#pragma unroll
            for (int k = 0; k < 9; ++k) bh[k] += (o == k) ? mag : 0.0f;  // o==9: none
        }

        // (5) rotate the rolling window (register renaming via full unroll)
#pragma unroll
        for (int k = 0; k < 8; ++k) { gp[k] = gm[k]; gm[k] = gn[k]; }
        if (pf) {
#pragma unroll
            for (int i = 0; i < 6; ++i) P[i] = N[i];
        }
    }

    // lane t == cell t: direct store, 9 consecutive dwords per lane
    float* hout = hist + ((size_t)(b * NCELL + cr) * NCELL + lane) * NORI;
#pragma unroll
    for (int k = 0; k < 9; ++k) hout[k] = bh[k] * 0.015625f;   // /64 cell area
}

// ---------------------------------------------------------------------------
// Kernel 2: 2x2 block gathering + double L2-hys normalization.
// (verified rounds 1/3) zero LDS, zero barriers. 4 lanes per output block
// (one cell each): 9 dword loads (hist L2-hot), quad shfl_xor butterflies
// for the norms, 9 dword stores per lane (block-contiguous).
// ---------------------------------------------------------------------------
__global__ __launch_bounds__(256) void hog_norm_kernel(const float* __restrict__ hist,
                                                       float* __restrict__ out) {
#pragma clang fp contract(off)
    const int bid = blockIdx.x;
    const int b   = bid / 63;
    const int r   = bid % 63;
    const int t   = threadIdx.x;
    const int c   = t >> 2;      // block column 0..63 (63 used)
    const int l   = t & 3;       // (i,j) within 2x2
    if (c >= 63) return;

    const int bi = l >> 1, bj = l & 1;
    const float* v = hist + ((size_t)(b * NCELL + r + bi) * NCELL + (c + bj)) * NORI;

    float vv[9];
    float ss = 0.0f;
#pragma unroll
    for (int k = 0; k < 9; ++k) { vv[k] = v[k]; ss += vv[k] * vv[k]; }
    ss += __shfl_xor(ss, 1, 64);
    ss += __shfl_xor(ss, 2, 64);
    const float rn1 = 1.0f / sqrtf(ss + 1e-10f);            // EPS^2 = 1e-10
    float ss2 = 0.0f;
#pragma unroll
    for (int k = 0; k < 9; ++k) { vv[k] = fminf(vv[k] * rn1, 0.2f); ss2 += vv[k] * vv[k]; }
    ss2 += __shfl_xor(ss2, 1, 64);
    ss2 += __shfl_xor(ss2, 2, 64);
    const float rn2 = 1.0f / sqrtf(ss2 + 1e-10f);

    float* od = out + (size_t)bid * (63 * 36) + (c * 36 + l * 9);
#pragma unroll
    for (int k = 0; k < 9; ++k) od[k] = vv[k] * rn2;
}

extern "C" void kernel_launch(void* const* d_in, const int* in_sizes, int n_in,
                              void* d_out, int out_size, void* d_ws, size_t ws_size,
                              hipStream_t stream) {
    const float* x = (const float*)d_in[0];
    float* out     = (float*)d_out;
    float* hist    = (float*)d_ws;   // 64*64*64*9 floats = 9.4 MB scratch

    hog_hist_kernel<<<dim3(64 * 16), dim3(256), 0, stream>>>(x, hist);
    hog_norm_kernel<<<dim3(64 * 63), dim3(256), 0, stream>>>(hist, out);
}

// Round 6
// 310.212 us; speedup vs baseline: 1.0012x; 1.0012x over previous
//
#include <hip/hip_runtime.h>
#include <math.h>

#define IMG_H 512
#define IMG_W 512
#define NCELL 64     // cells per dim (512/8)
#define NORI 9

// ---------------------------------------------------------------------------
// Bit-exact transcription of glibc/FDLIBM float atan / atan2 (flt-32 Sun code)
// — what numpy's np.arctan2 float32 loop resolves to on glibc <= 2.40.
// INLINED (verified rounds 2-4): runtime-indexed tables converted to selects
// so nothing spills to scratch. Reached only for ~5e-4 of pixels, and only
// from COLD post-loop code (3 inlined copies total, none in the hot loop).
// ---------------------------------------------------------------------------
__device__ __forceinline__ float fdlibm_atanf_inl(float x) {
#pragma clang fp contract(off)
    const float one = 1.0f;
    int hx = __float_as_int(x);
    int ix = hx & 0x7fffffff;
    int id;
    if (ix >= 0x4c800000) {                 // |x| >= 2^26
        const float v = 1.5707962513e+00f + 7.5497894159e-08f;  // folded in f32
        return (hx > 0) ? v : -v;
    }
    if (ix < 0x3ee00000) {                  // |x| < 0.4375
        if (ix < 0x39800000) return x;      // |x| < 2^-12
        id = -1;
    } else {
        x = fabsf(x);
        if (ix < 0x3f980000) {              // |x| < 1.1875
            if (ix < 0x3f300000) { id = 0; x = (2.0f * x - one) / (2.0f + x); }
            else                 { id = 1; x = (x - one) / (x + one); }
        } else {
            if (ix < 0x401c0000) { id = 2; x = (x - 1.5f) / (one + 1.5f * x); }
            else                 { id = 3; x = -1.0f / x; }
        }
    }
    float z = x * x;
    float w = z * z;
    float s1 = z * (3.3333334327e-01f + w * (1.4285714924e-01f + w * (9.0908870101e-02f
             + w * (6.6610731184e-02f + w * (4.9768779427e-02f + w * 1.6285819933e-02f)))));
    float s2 = w * (-2.0000000298e-01f + w * (-1.1111110449e-01f + w * (-7.6918758452e-02f
             + w * (-5.8335702866e-02f + w * -3.6531571299e-02f))));
    if (id < 0) return x - x * (s1 + s2);
    const float hi = (id == 0) ? 4.6364760399e-01f : (id == 1) ? 7.8539812565e-01f
                   : (id == 2) ? 9.8279368877e-01f : 1.5707962513e+00f;
    const float lo = (id == 0) ? 5.0121582440e-09f : (id == 1) ? 3.7748947079e-08f
                   : (id == 2) ? 3.4473217170e-08f : 7.5497894159e-08f;
    z = hi - ((x * (s1 + s2) - lo) - x);
    return (hx < 0) ? -z : z;
}

__device__ __forceinline__ int fdlibm_bin_inl(float y, float x) {
#pragma clang fp contract(off)
    // exact reference chain: fdlibm atan2f -> f32 rad2deg -> numpy mod -> bin
    const float tiny   = 1.0e-30f;
    const float pi_o_2 = 1.5707963705e+00f;   // 0x3FC90FDB
    const float pi     = 3.1415927410e+00f;   // 0x40490FDB
    const float pi_lo  = -8.7422776573e-08f;  // 0xB3BBBD2E

    int hx = __float_as_int(x), ix = hx & 0x7fffffff;
    int hy = __float_as_int(y), iy = hy & 0x7fffffff;
    float th;
    if (hx == 0x3f800000) { th = fdlibm_atanf_inl(y); }    // x == 1.0
    else {
        int m = ((hy >> 31) & 1) | ((hx >> 30) & 2);       // 2*sign(x)+sign(y)
        if (iy == 0) {                                      // y == +-0
            switch (m) {
                case 0:
                case 1: th = y; break;
                case 2: th =  pi + tiny; break;
                default: th = -pi - tiny; break;
            }
        } else if (ix == 0) {
            th = (hy < 0) ? -pi_o_2 - tiny : pi_o_2 + tiny; // x == +-0
        } else {
            int k = (iy - ix) >> 23;
            float z;
            int mm = m;
            if (k > 26) {                                   // |y/x| > 2^26
                z = pi_o_2 + 0.5f * pi_lo;
                mm &= 1;
            } else if (k < -26 && hx < 0) {
                z = 0.0f;
            } else {
                z = fdlibm_atanf_inl(fabsf(y / x));
            }
            switch (mm) {
                case 0:  th = z; break;
                case 1:  th = -z; break;
                case 2:  th = pi - (z - pi_lo); break;
                default: th = (z - pi_lo) - pi; break;
            }
        }
    }
    const float RAD2DEG = (float)(180.0 / 3.14159265358979311600e+00);
    float m = fmodf(th * RAD2DEG, 180.0f);                  // numpy remainder semantics
    if (m < 0.0f) m += 180.0f;                              // (can round up to exactly 180)
    int o = (int)(m * 0.05f);
    if (o < 9) {                                            // exact boundary fix-up
        if (m < 20.0f * (float)o) --o;
        else if (m >= 20.0f * (float)(o + 1)) ++o;
    }
    return o;                                               // may be 9 (== exactly 180): no bin
}

// ---------------------------------------------------------------------------
// Kernel 1 v5 (resubmit — round 5 bench was an infra failure, not a verdict):
// per-cell orientation histograms, COALESCED staging.
// R3 skeleton (512 thr, LDS gray, sector tests, butterfly store) with the
// staging rebuilt: raw RGB rows loaded with lane-consecutive float4 (each
// wave = 1KB contiguous) into a 30KB LDS buffer, then raw->gray conversion
// from LDS (stride-3 word reads: coprime with 32 banks, conflict-free).
// Two 5-row phases reuse the raw buffer (51.2KB total LDS, 3 blocks/CU).
// Suspect slow path deferred OUT of the hot loop: static 2-slot record +
// cold post-loop resolve (deterministic rescan fallback if >2 per thread).
// ---------------------------------------------------------------------------
__global__ __launch_bounds__(512, 6) void hog_hist_kernel(const float* __restrict__ x,
                                                          float* __restrict__ hist) {
#pragma clang fp contract(off)
    const int bid = blockIdx.x;
    const int b   = bid >> 6;     // batch
    const int cr  = bid & 63;     // cell row
    const int t   = threadIdx.x;
    const int h0  = cr * 8;

    __shared__ __align__(16) float4 raw[1920];        // 30 KB: 5 raw RGB rows
    __shared__ __align__(16) float  g[10][IMG_W];     // 20 KB gray strip + halos

    const float GW0 = 0.2125f, GW1 = 0.7154f, GW2 = 0.0721f;

#pragma unroll
    for (int p = 0; p < 2; ++p) {
        // ---- stage 5 rows, perfectly coalesced (wave covers 1KB contiguous) ----
        for (int i = t; i < 1920; i += 512) {
            const int rr  = i / 384;              // row within phase (384 f4/row)
            const int idx = i - rr * 384;
            int h = h0 - 1 + p * 5 + rr;          // mirror-clamp: edge gr == +0.0
            if (h < 0)   h = 1;
            if (h > 511) h = 510;
            raw[i] = ((const float4*)x)[(size_t)(b * IMG_H + h) * 384 + idx];
        }
        __syncthreads();
        // ---- convert raw -> gray; stride-3 LDS word reads are conflict-free ----
        const float* rf = (const float*)raw;
#pragma unroll
        for (int k = 0; k < 5; ++k) {
            const float r_ = rf[k * 1536 + 3 * t + 0];
            const float g_ = rf[k * 1536 + 3 * t + 1];
            const float b_ = rf[k * 1536 + 3 * t + 2];
            g[p * 5 + k][t] = __builtin_fmaf(b_, GW2, __builtin_fmaf(g_, GW1, r_ * GW0));
        }
        __syncthreads();   // p=0: raw free for reuse; p=1: gray complete
    }

    // ---- per-pixel gradient, magnitude, orientation bin (one column/thread) ----
    const int w   = t;                              // pixel column 0..511
    const int wl  = (w == 0)   ? 0   : w - 1;
    const int wr  = (w == 511) ? 511 : w + 1;
    const bool wok = (w >= 1) && (w <= 510);
    const int c   = w >> 3;                         // cell column
    const int jl  = t & 7;                          // lane within cell

    // batch-preload: all independent ds_reads issued up front
    float cc[10], ee[8], ww[8];
#pragma unroll
    for (int i = 0; i < 10; ++i) cc[i] = g[i][w];
#pragma unroll
    for (int i = 0; i < 8; ++i) { ee[i] = g[i + 1][wr]; ww[i] = g[i + 1][wl]; }

    // sector boundary constants (20k degrees), f32-rounded
    const float CK[8] = { 0.9396926208f,  0.7660444431f,  0.5f,            0.1736481777f,
                         -0.1736481777f, -0.5f,           -0.7660444431f, -0.9396926208f };
    const float SK[8] = { 0.3420201433f,  0.6427876097f,  0.8660254038f,  0.9848077530f,
                          0.9848077530f,  0.8660254038f,  0.6427876097f,  0.3420201433f };

    float bh[9];
#pragma unroll
    for (int k = 0; k < 9; ++k) bh[k] = 0.0f;

    // deferred-suspect slots (static names: no runtime indexing -> no scratch)
    int   nsus = 0;
    float s0gr = 0.0f, s0gc = 0.0f, s0mag = 0.0f;
    float s1gr = 0.0f, s1gc = 0.0f, s1mag = 0.0f;

#pragma unroll
    for (int r = 0; r < 8; ++r) {
        const float gr = cc[r + 2] - cc[r];              // +0.0 at image edge rows
        const float gc = wok ? (ee[r] - ww[r]) : 0.0f;
        const float mag = __builtin_amdgcn_sqrtf(__builtin_fmaf(gr, gr, gc * gc));

        const float gy = fabsf(gr);
        const float gx = (gr < 0.0f) ? -gc : gc;         // theta mod 180 representative
        const float th = 1e-4f * mag;                    // suspect margin (~0.006 deg)
        int  o = 0;
        bool suspect = false;
#pragma unroll
        for (int k = 0; k < 8; ++k) {
            const float ck = __builtin_fmaf(gy, CK[k], -(gx * SK[k]));
            o += (ck >= 0.0f) ? 1 : 0;
            suspect = suspect || (fabsf(ck) < th);
        }
        // f32 near-180 zone: atan2f can round to pi exactly -> ref deg>=180 ->
        // mod wraps to bin 0 / no-bin. Sector test can't see this; defer.
        suspect = suspect || ((gx < 0.0f) && (gy < 1e-5f * fabsf(gc)));
        if (gy == 0.0f) { o = 0; suspect = false; }      // exact: ref chain -> bin 0
        if (__builtin_expect(suspect, 0)) {              // defer; hot loop stays clean
            if (nsus == 0)      { s0gr = gr; s0gc = gc; s0mag = mag; }
            else if (nsus == 1) { s1gr = gr; s1gc = gc; s1mag = mag; }
            ++nsus;
            o = 9;                                       // no accumulate now
        }
#pragma unroll
        for (int k = 0; k < 9; ++k) bh[k] += (o == k) ? mag : 0.0f;  // o==9: none
    }

    // ---- cold path: resolve deferred suspects with the exact fdlibm chain ----
    if (__builtin_expect(nsus > 0, 0)) {
        if (nsus <= 2) {
            {
                const int o = fdlibm_bin_inl(s0gr, s0gc);
                if (o < 9) bh[o] += s0mag;
            }
            if (nsus == 2) {
                const int o = fdlibm_bin_inl(s1gr, s1gc);
                if (o < 9) bh[o] += s1mag;
            }
        } else {
            // >2 suspects in one thread (P ~ 1e-2 per launch): deterministic
            // rescan of this thread's 8 pixels; identical arithmetic ->
            // identical suspect set; slots ignored (hot loop added nothing).
            for (int r = 0; r < 8; ++r) {
                const float gr = g[r + 2][w] - g[r][w];
                const float gc = wok ? (g[r + 1][wr] - g[r + 1][wl]) : 0.0f;
                const float mag = __builtin_amdgcn_sqrtf(__builtin_fmaf(gr, gr, gc * gc));
                const float gy = fabsf(gr);
                const float gx = (gr < 0.0f) ? -gc : gc;
                const float th = 1e-4f * mag;
                bool suspect = false;
                for (int k = 0; k < 8; ++k) {
                    const float ck = __builtin_fmaf(gy, CK[k], -(gx * SK[k]));
                    suspect = suspect || (fabsf(ck) < th);
                }
                suspect = suspect || ((gx < 0.0f) && (gy < 1e-5f * fabsf(gc)));
                if (gy == 0.0f) suspect = false;
                if (suspect) {
                    const int o = fdlibm_bin_inl(gr, gc);
                    if (o < 9) bh[o] += mag;
                }
            }
        }
    }

    // reduce the 8 lanes of each cell (lanes are contiguous groups of 8)
#pragma unroll
    for (int k = 0; k < 9; ++k) {
        bh[k] += __shfl_xor(bh[k], 1, 64);
        bh[k] += __shfl_xor(bh[k], 2, 64);
        bh[k] += __shfl_xor(bh[k], 4, 64);
    }
    // lane jl of the cell stores bin jl (contiguous across the wave), lane 0 bin 8
    float mv = bh[0];
#pragma unroll
    for (int k = 1; k < 8; ++k) mv = (jl == k) ? bh[k] : mv;
    float* hout = hist + (size_t)(b * NCELL + cr) * (NCELL * NORI);
    hout[c * NORI + jl] = mv * 0.015625f;                // /64 cell area
    if (jl == 0) hout[c * NORI + 8] = bh[8] * 0.015625f;
}

// ---------------------------------------------------------------------------
// Kernel 2: 2x2 block gathering + double L2-hys normalization.
// (verified rounds 1/3/4) zero LDS, zero barriers. 4 lanes per output block
// (one cell each): 9 dword loads (hist L2-hot), quad shfl_xor butterflies
// for the norms, 9 dword stores per lane (block-contiguous).
// ---------------------------------------------------------------------------
__global__ __launch_bounds__(256) void hog_norm_kernel(const float* __restrict__ hist,
                                                       float* __restrict__ out) {
#pragma clang fp contract(off)
    const int bid = blockIdx.x;
    const int b   = bid / 63;
    const int r   = bid % 63;
    const int t   = threadIdx.x;
    const int c   = t >> 2;      // block column 0..63 (63 used)
    const int l   = t & 3;       // (i,j) within 2x2
    if (c >= 63) return;

    const int bi = l >> 1, bj = l & 1;
    const float* v = hist + ((size_t)(b * NCELL + r + bi) * NCELL + (c + bj)) * NORI;

    float vv[9];
    float ss = 0.0f;
#pragma unroll
    for (int k = 0; k < 9; ++k) { vv[k] = v[k]; ss += vv[k] * vv[k]; }
    ss += __shfl_xor(ss, 1, 64);
    ss += __shfl_xor(ss, 2, 64);
    const float rn1 = 1.0f / sqrtf(ss + 1e-10f);            // EPS^2 = 1e-10
    float ss2 = 0.0f;
#pragma unroll
    for (int k = 0; k < 9; ++k) { vv[k] = fminf(vv[k] * rn1, 0.2f); ss2 += vv[k] * vv[k]; }
    ss2 += __shfl_xor(ss2, 1, 64);
    ss2 += __shfl_xor(ss2, 2, 64);
    const float rn2 = 1.0f / sqrtf(ss2 + 1e-10f);

    float* od = out + (size_t)bid * (63 * 36) + (c * 36 + l * 9);
#pragma unroll
    for (int k = 0; k < 9; ++k) od[k] = vv[k] * rn2;
}

extern "C" void kernel_launch(void* const* d_in, const int* in_sizes, int n_in,
                              void* d_out, int out_size, void* d_ws, size_t ws_size,
                              hipStream_t stream) {
    const float* x = (const float*)d_in[0];
    float* out     = (float*)d_out;
    float* hist    = (float*)d_ws;   // 64*64*64*9 floats = 9.4 MB scratch

    hog_hist_kernel<<<dim3(64 * 64), dim3(512), 0, stream>>>(x, hist);
    hog_norm_kernel<<<dim3(64 * 63), dim3(256), 0, stream>>>(hist, out);
}